// Round 6
// baseline (1152.505 us; speedup 1.0000x reference)
//
#include <hip/hip_runtime.h>
#include <math.h>

#define NCLASSES   10000
#define NCLASSES4  2500            // NCLASSES / 4
#define NT         256             // threads per block (4 waves)
#define NITER      10              // ceil(2500/256)
#define IGNORE_INDEX (-1)

#define SMOOTH_UNIF  1e-5          // SMOOTHING / CLASSES
#define SMOOTH_COMPL 0.9           // 1 - SMOOTHING

// Single-pass focal CE via moment decomposition:
//   (1-p)^3 * ls = (1 - 3p + 3p^2 - p^3) * ls,  p = e^x / Z, ls = x - lse
//   => sum_j w_j is a linear combination of
//      S0=Σx, Z1=Σe^x, A1=Σe^x·x, Z2=Σe^2x, A2=Σe^2x·x, Z3=Σe^3x, A3=Σe^3x·x
// Per-row results land in ws; an INTEGER ticket (native RMW, no CAS loop —
// fp32 atomicAdd compiles to a CAS loop and serialized for ~700us in R3/R5)
// elects the last block, which reduces the 8192-pair array and writes out.
__global__ __launch_bounds__(NT)
void focal_ce_moments(const float* __restrict__ logits,
                      const int* __restrict__ target,
                      float* __restrict__ tok_loss,
                      float* __restrict__ tok_mask,
                      unsigned* __restrict__ ticket,
                      float* __restrict__ out,
                      int n_rows) {
    const int row = blockIdx.x;
    const int t = threadIdx.x;
    const float* __restrict__ xrow = logits + (size_t)row * NCLASSES;
    const float4* __restrict__ xrow4 = reinterpret_cast<const float4*>(xrow);
    const int tgt = target[row];

    // thread 0 fetches the target logit directly (one 4B load)
    float xt = 0.0f;
    if (t == 0 && tgt >= 0) xt = xrow[tgt];

    // ---- pass 1: pure loads into a register array (keeps 10 loads in
    // ---- flight per thread; R2-measured-fast codegen shape) ----
    float4 v[NITER];
    #pragma unroll
    for (int i = 0; i < NITER; i++) {
        int idx4 = t + i * NT;
        if (idx4 < NCLASSES4)               // only i==9 can fail
            v[i] = xrow4[idx4];
        else
            v[i] = make_float4(0.f, 0.f, 0.f, 0.f);
    }

    // ---- pass 2: moments (exp of 0-padding contributes a known constant,
    // ---- removed below: npad lanes add e^0=1 to z1,z2,z3 and 0 to s0,a*) ----
    float s0 = 0.f, z1 = 0.f, a1 = 0.f, z2 = 0.f, a2 = 0.f, z3 = 0.f, a3 = 0.f;
    #pragma unroll
    for (int i = 0; i < NITER; i++) {
        float xs[4] = { v[i].x, v[i].y, v[i].z, v[i].w };
        #pragma unroll
        for (int c = 0; c < 4; c++) {
            float x = xs[c];
            float e = __expf(x), e2 = e * e, e3 = e2 * e;
            s0 += x; z1 += e; z2 += e2; z3 += e3;
            a1 = fmaf(e, x, a1); a2 = fmaf(e2, x, a2); a3 = fmaf(e3, x, a3);
        }
    }

    // ---- block reduce of the 7 moments ----
    #pragma unroll
    for (int off = 32; off > 0; off >>= 1) {
        s0 += __shfl_down(s0, off, 64);
        z1 += __shfl_down(z1, off, 64);
        a1 += __shfl_down(a1, off, 64);
        z2 += __shfl_down(z2, off, 64);
        a2 += __shfl_down(a2, off, 64);
        z3 += __shfl_down(z3, off, 64);
        a3 += __shfl_down(a3, off, 64);
    }
    __shared__ float red[7][NT / 64];
    const int w = t >> 6;
    if ((t & 63) == 0) {
        red[0][w] = s0; red[1][w] = z1; red[2][w] = a1;
        red[3][w] = z2; red[4][w] = a2; red[5][w] = z3; red[6][w] = a3;
    }
    __syncthreads();

    if (t == 0) {
        double S0 = 0, Z1 = 0, A1 = 0, Z2 = 0, A2 = 0, Z3 = 0, A3 = 0;
        #pragma unroll
        for (int j = 0; j < NT / 64; j++) {
            S0 += red[0][j]; Z1 += red[1][j]; A1 += red[2][j];
            Z2 += red[3][j]; A2 += red[4][j]; Z3 += red[5][j]; A3 += red[6][j];
        }
        // remove the 0-padding lanes' e^0 = 1 contributions
        const double npad = (double)(NITER * NT * 4 - NCLASSES);   // 240
        Z1 -= npad; Z2 -= npad; Z3 -= npad;

        float loss = 0.0f, msk = 0.0f;
        if (tgt != IGNORE_INDEX) {
            double lse = log(Z1);
            double SL = S0 - (double)NCLASSES * lse;         // Σ ls
            double T1 = (A1 - lse * Z1) / Z1;                // Σ p·ls
            double T2 = (A2 - lse * Z2) / (Z1 * Z1);         // Σ p²·ls
            double T3 = (A3 - lse * Z3) / (Z1 * Z1 * Z1);    // Σ p³·ls
            double W = SL - 3.0 * T1 + 3.0 * T2 - T3;
            double ls_t = (double)xt - lse;
            double pt = exp(ls_t);
            double om = 1.0 - pt;
            double w_t = om * om * om * ls_t;
            loss = (float)(-(SMOOTH_UNIF * W + SMOOTH_COMPL * w_t));
            msk = 1.0f;
        }
        tok_loss[row] = loss;
        tok_mask[row] = msk;
    }
    __syncthreads();   // all threads wait so last-block election follows writes

    // ---- last-block election via native integer atomic (no CAS loop) ----
    __shared__ unsigned s_prev;
    if (t == 0) {
        __threadfence();   // release tok_loss/tok_mask to device scope
        s_prev = __hip_atomic_fetch_add(ticket, 1u, __ATOMIC_ACQ_REL,
                                        __HIP_MEMORY_SCOPE_AGENT);
    }
    __syncthreads();
    if (s_prev == (unsigned)(n_rows - 1)) {
        // last block: reduce all rows; agent-scope loads avoid stale L1
        double s = 0.0, c = 0.0;
        for (int i = t; i < n_rows; i += NT) {
            s += (double)__hip_atomic_load(&tok_loss[i], __ATOMIC_RELAXED,
                                           __HIP_MEMORY_SCOPE_AGENT);
            c += (double)__hip_atomic_load(&tok_mask[i], __ATOMIC_RELAXED,
                                           __HIP_MEMORY_SCOPE_AGENT);
        }
        #pragma unroll
        for (int off = 32; off > 0; off >>= 1) {
            s += __shfl_down(s, off, 64);
            c += __shfl_down(c, off, 64);
        }
        __shared__ double tmp_s[NT / 64], tmp_c[NT / 64];
        if ((t & 63) == 0) { tmp_s[t >> 6] = s; tmp_c[t >> 6] = c; }
        __syncthreads();
        if (t == 0) {
            double S = 0.0, C = 0.0;
            #pragma unroll
            for (int j = 0; j < NT / 64; j++) { S += tmp_s[j]; C += tmp_c[j]; }
            out[0] = (float)(S / C);
        }
    }
}

extern "C" void kernel_launch(void* const* d_in, const int* in_sizes, int n_in,
                              void* d_out, int out_size, void* d_ws, size_t ws_size,
                              hipStream_t stream) {
    const float* logits = (const float*)d_in[0];
    const int* target = (const int*)d_in[1];
    const int n_tok = in_sizes[1];          // B*S = 8192

    float* tok_loss = (float*)d_ws;
    float* tok_mask = tok_loss + n_tok;
    unsigned* ticket = (unsigned*)(tok_mask + n_tok);

    // zero only the ticket (4 B); tok arrays are fully overwritten
    hipMemsetAsync(ticket, 0, 4, stream);

    focal_ce_moments<<<n_tok, NT, 0, stream>>>(logits, target, tok_loss,
                                               tok_mask, ticket,
                                               (float*)d_out, n_tok);
}